// Round 10
// baseline (453.500 us; speedup 1.0000x reference)
//
#include <hip/hip_runtime.h>
#include <hip/hip_cooperative_groups.h>
#include <math.h>
#include <stdint.h>

namespace cg = cooperative_groups;

#define C_ 256
#define HW_ 4096
#define PLANE (C_*HW_)   // 1048576 elements per batch
#define INV_CNT (1.f / 131072.f)
#define NSLOT 16         // atomic spread slots per (tensor,b,g)
#define PSTRIDE 264      // padded LDS stride (shorts) for pos transpose tile

typedef __attribute__((ext_vector_type(8))) short bf16x8;
typedef __attribute__((ext_vector_type(4))) float f32x4;

__device__ __forceinline__ unsigned short f2bf(float f) {
    union { float f; unsigned int u; } v; v.f = f;
    unsigned int r = v.u + 0x7fffu + ((v.u >> 16) & 1u);
    return (unsigned short)(r >> 16);
}

__device__ __forceinline__ float bf2f(unsigned short u) {
    return __uint_as_float(((unsigned)u) << 16);
}

__device__ __forceinline__ void load_lds16(const void* g, void* l) {
    __builtin_amdgcn_global_load_lds(
        (const __attribute__((address_space(1))) unsigned int*)g,
        (__attribute__((address_space(3))) unsigned int*)l, 16, 0, 0);
}

__device__ __forceinline__ void bf16x32_load(const unsigned short* p, float* o) {
    const uint4* u4 = (const uint4*)p;
#pragma unroll
    for (int i = 0; i < 4; i++) {
        uint4 u = u4[i];
        o[i*8+0] = __uint_as_float(u.x << 16); o[i*8+1] = __uint_as_float(u.x & 0xffff0000u);
        o[i*8+2] = __uint_as_float(u.y << 16); o[i*8+3] = __uint_as_float(u.y & 0xffff0000u);
        o[i*8+4] = __uint_as_float(u.z << 16); o[i*8+5] = __uint_as_float(u.z & 0xffff0000u);
        o[i*8+6] = __uint_as_float(u.w << 16); o[i*8+7] = __uint_as_float(u.w & 0xffff0000u);
    }
}

// MFMA core, BK=64 as two BK=32 sub-buffers. Caller provides 32 KB of LDS.
__device__ __forceinline__ void mfma_core(
    const unsigned short* __restrict__ A,
    const unsigned short* __restrict__ Bm,
    int m0, int n0, f32x4 (&acc)[4][4],
    unsigned short* sA, unsigned short* sB)
{
    const int t = threadIdx.x;
    const int lane = t & 63, wave = t >> 6;

#pragma unroll
    for (int i = 0; i < 4; i++)
#pragma unroll
        for (int j = 0; j < 4; j++) acc[i][j] = (f32x4)0.f;

    const int srow = wave * 32 + (lane >> 2);
    const int scol = (lane & 3) * 8;
    const unsigned short* ga = A  + (size_t)(m0 + srow) * 256 + scol;
    const unsigned short* gb = Bm + (size_t)(n0 + srow) * 256 + scol;
    const int lbase = (wave * 32) * 32;

    const int wm = wave >> 1, wn = wave & 1;
    const int fr = lane & 15, kg = lane >> 4;

    for (int k0 = 0; k0 < 256; k0 += 64) {
        if (k0) __syncthreads();
        load_lds16(ga + k0,            sA + lbase);
        load_lds16(ga + k0 + 16 * 256, sA + lbase + 16 * 32);
        load_lds16(gb + k0,            sB + lbase);
        load_lds16(gb + k0 + 16 * 256, sB + lbase + 16 * 32);
        load_lds16(ga + k0 + 32,            sA + 4096 + lbase);
        load_lds16(ga + k0 + 32 + 16 * 256, sA + 4096 + lbase + 16 * 32);
        load_lds16(gb + k0 + 32,            sB + 4096 + lbase);
        load_lds16(gb + k0 + 32 + 16 * 256, sB + 4096 + lbase + 16 * 32);
        __syncthreads();

#pragma unroll
        for (int kk = 0; kk < 2; kk++) {
            bf16x8 af[4], bfr[4];
#pragma unroll
            for (int i = 0; i < 4; i++) {
                af[i]  = *(const bf16x8*)(sA + kk * 4096 + (wm * 64 + i * 16 + fr) * 32 + kg * 8);
                bfr[i] = *(const bf16x8*)(sB + kk * 4096 + (wn * 64 + i * 16 + fr) * 32 + kg * 8);
            }
#pragma unroll
            for (int mi = 0; mi < 4; mi++)
#pragma unroll
                for (int ni = 0; ni < 4; ni++)
                    acc[mi][ni] = __builtin_amdgcn_mfma_f32_16x16x32_bf16(
                        af[mi], bfr[ni], acc[mi][ni], 0, 0, 0);
        }
    }
}

__device__ __forceinline__ void stat_atomic(
    float s0, float ss0, float s1, float ss1, float* d0, float* d1)
{
#pragma unroll
    for (int off = 32; off >= 1; off >>= 1) {
        s0  += __shfl_down(s0, off);  ss0 += __shfl_down(ss0, off);
        s1  += __shfl_down(s1, off);  ss1 += __shfl_down(ss1, off);
    }
    if ((threadIdx.x & 63) == 0) {
        atomicAdd(d0, s0); atomicAdd(d0 + 1, ss0);
        atomicAdd(d1, s1); atomicAdd(d1 + 1, ss1);
    }
}

__device__ __forceinline__ void stat_read(const float* sp, float& S, float& SS) {
    S = 0.f; SS = 0.f;
#pragma unroll
    for (int i = 0; i < NSLOT; i++) { S += sp[i * 2]; SS += sp[i * 2 + 1]; }
}

__device__ __forceinline__ float gelu_exact(float v) {
    return 0.5f * v * (1.f + erff(v * 0.70710678118654752f));
}

struct MegaParams {
    const float* x;
    const float* wq; const float* wk; const float* wv; const float* wp;
    const float* bp;
    const float* gqg; const float* gqb; const float* gkg; const float* gkb;
    const float* gpg; const float* gpb;
    const float* dw1; const float* db1; const float* dw2; const float* db2;
    unsigned short* xT;     // 8 MB bf16 [n][c]; reused as aT after qkv
    unsigned short* wbf;    // 512 KB bf16 weights
    unsigned short* qtok; unsigned short* ktok; unsigned short* vtok;
    unsigned short* pos;    // 8 MB bf16 channel-major
    float* stats;           // 3072 floats
    float* out;             // d_out fp32
};

// ---------------------------------------------------------------------------
// One cooperative kernel, phases separated by grid syncs.
// LDS arena 35904 B (max over phases). 3 blocks/CU via launch_bounds(256,3).
// ---------------------------------------------------------------------------
__global__ __launch_bounds__(256, 3) void mega_kernel(MegaParams P)
{
    __shared__ __align__(16) char smem[66 * 68 * 4 * 2];   // 35904 B
    cg::grid_group grid = cg::this_grid();
    const int bid = blockIdx.x;
    const int NBg = gridDim.x;
    const int t = threadIdx.x;

    // ---------------- Phase 1a: transpose x -> xT + weight cvt + stats zero
    {
        float (*tile)[65] = (float(*)[65])smem;
        for (int u = bid; u < 1024; u += NBg) {
            int widx = u * 256 + t;
            const float* wsrc = (widx < 65536) ? P.wq : (widx < 131072) ? P.wk
                              : (widx < 196608) ? P.wv : P.wp;
            P.wbf[widx] = f2bf(wsrc[widx & 65535]);
            if (u == 0) {
#pragma unroll
                for (int i = 0; i < 12; i++) P.stats[t + i * 256] = 0.f;
            }
            int b = u >> 8, c0 = ((u >> 6) & 3) * 64, n0 = (u & 63) * 64;
            const float* s = P.x + (size_t)b * PLANE;
            unsigned short* d = P.xT + (size_t)b * PLANE;
            int r = t >> 6, col = t & 63;
            __syncthreads();
#pragma unroll
            for (int i = 0; i < 16; i++)
                tile[r + i * 4][col] = s[(size_t)(c0 + r + i * 4) * HW_ + n0 + col];
            __syncthreads();
#pragma unroll
            for (int i = 0; i < 16; i++)
                d[(size_t)(n0 + r + i * 4) * 256 + c0 + col] = f2bf(tile[col][r + i * 4]);
        }
    }

    // ---------------- Phase 1b: depthwise conv -> GELU -> depthwise conv
    {
        float* xs = (float*)smem;
        float* ps = xs + 66 * 68;
        for (int u = bid; u < 1024; u += NBg) {   // u = b*256 + c
            int c = u & 255;
            const float* plane = P.x + (size_t)u * 4096;
            float w1[9], w2[9];
#pragma unroll
            for (int i = 0; i < 9; i++) { w1[i] = P.dw1[c * 9 + i]; w2[i] = P.dw2[c * 9 + i]; }
            const float b1 = P.db1[c], b2 = P.db2[c];
            __syncthreads();
            for (int i = t; i < 66 * 66; i += 256) {
                int r = i / 66, cc = i - r * 66;
                int gr = r - 1, gc = cc - 1;
                float v = 0.f;
                if ((unsigned)gr < 64u && (unsigned)gc < 64u) v = plane[gr * 64 + gc];
                xs[r * 68 + cc] = v;
            }
            __syncthreads();
            for (int i = t; i < 66 * 66; i += 256) {
                int pr = i / 66, pc = i - pr * 66;
                int gr = pr - 1, gc = pc - 1;
                float val = 0.f;
                if ((unsigned)gr < 64u && (unsigned)gc < 64u) {
                    float s = b1;
#pragma unroll
                    for (int ky = 0; ky < 3; ky++)
#pragma unroll
                        for (int kx = 0; kx < 3; kx++)
                            s += w1[ky * 3 + kx] * xs[(gr + ky) * 68 + (gc + kx)];
                    val = gelu_exact(s);
                }
                ps[pr * 68 + pc] = val;
            }
            __syncthreads();
            for (int i = t; i < 4096; i += 256) {
                int orow = i >> 6, ocol = i & 63;
                float s = b2;
#pragma unroll
                for (int ky = 0; ky < 3; ky++)
#pragma unroll
                    for (int kx = 0; kx < 3; kx++)
                        s += w2[ky * 3 + kx] * ps[(orow + ky) * 68 + (ocol + kx)];
                P.pos[(size_t)u * 4096 + i] = f2bf(s);
            }
        }
    }

    grid.sync();

    // ---------------- Phase 2: q/k/v GEMM (768 tiles)
    {
        unsigned short* sA = (unsigned short*)smem;
        unsigned short* sB = (unsigned short*)(smem + 16384);
        for (int u = bid; u < 768; u += NBg) {
            int z = u >> 6, rr = u & 63;
            int batch = z & 3, which = z >> 2;
            unsigned short* Y = ((which == 0) ? P.qtok : (which == 1) ? P.ktok : P.vtok)
                                + (size_t)batch * PLANE;
            const unsigned short* A  = P.wbf + which * 65536;          // outch x K
            const unsigned short* Bm = P.xT + (size_t)batch * PLANE;   // token x K
            const int m0 = (rr & 1) * 128;     // outch
            const int n0 = (rr >> 1) * 128;    // token

            __syncthreads();
            f32x4 acc[4][4];
            mfma_core(A, Bm, m0, n0, acc, sA, sB);

            const int lane = t & 63, wave = t >> 6;
            const int wm = wave >> 1, wn = wave & 1;
            const int cl = lane & 15, qd = lane >> 4;

            if (which < 2) {
                float s[2] = {0.f, 0.f}, ss[2] = {0.f, 0.f};
#pragma unroll
                for (int mi = 0; mi < 4; mi++)
#pragma unroll
                    for (int ni = 0; ni < 4; ni++)
#pragma unroll
                        for (int r = 0; r < 4; r++) {
                            float vv = acc[mi][ni][r];
                            s[mi >> 1] += vv; ss[mi >> 1] += vv * vv;
                        }
                int g0 = (m0 >> 5) + wm * 2;
                int slot = (rr >> 1) & (NSLOT - 1);
                float* d0 = P.stats + (size_t)(which * 32 + batch * 8 + g0) * (NSLOT * 2) + slot * 2;
                stat_atomic(s[0], ss[0], s[1], ss[1], d0, d0 + NSLOT * 2);
            }

#pragma unroll
            for (int mi = 0; mi < 4; mi++) {
                int oc = m0 + wm * 64 + mi * 16 + qd * 4;
#pragma unroll
                for (int ni = 0; ni < 4; ni++) {
                    int token = n0 + wn * 64 + ni * 16 + cl;
                    uint2 pk;
                    pk.x = (unsigned)f2bf(acc[mi][ni][0]) | ((unsigned)f2bf(acc[mi][ni][1]) << 16);
                    pk.y = (unsigned)f2bf(acc[mi][ni][2]) | ((unsigned)f2bf(acc[mi][ni][3]) << 16);
                    *(uint2*)&Y[(size_t)token * 256 + oc] = pk;
                }
            }
        }
    }

    grid.sync();

    // ---------------- Phase 3: attention + pos-add (512 units of 32 pixels)
    {
        float* sqg = (float*)smem;
        float* sqb = sqg + 256;
        float* skg = sqg + 512;
        float* skb = sqg + 768;
        unsigned short* ptile = (unsigned short*)(smem + 4096);   // 32 x PSTRIDE
        unsigned short* aT = P.xT;   // xT is dead after phase 2
        sqg[t] = P.gqg[t]; sqb[t] = P.gqb[t]; skg[t] = P.gkg[t]; skb[t] = P.gkb[t];

        const float K2 = 0.17677669529663687f * 1.4426950408889634f; // scale*log2e
        const int h = t & 7;
        const int p = t >> 3;

        for (int u = bid; u < 512; u += NBg) {
            const int pix0 = u * 32;
            const int b = pix0 >> 12;
            const int n0 = pix0 & 4095;
            __syncthreads();
            // stage pos^T: thread t = channel t, 32 consecutive pixels
            {
                const uint4* prow = (const uint4*)(P.pos + (size_t)b * PLANE + (size_t)t * HW_ + n0);
#pragma unroll
                for (int i = 0; i < 4; i++) {
                    uint4 uu = prow[i];
                    ptile[(i*8+0) * PSTRIDE + t] = (unsigned short)(uu.x & 0xffff);
                    ptile[(i*8+1) * PSTRIDE + t] = (unsigned short)(uu.x >> 16);
                    ptile[(i*8+2) * PSTRIDE + t] = (unsigned short)(uu.y & 0xffff);
                    ptile[(i*8+3) * PSTRIDE + t] = (unsigned short)(uu.y >> 16);
                    ptile[(i*8+4) * PSTRIDE + t] = (unsigned short)(uu.z & 0xffff);
                    ptile[(i*8+5) * PSTRIDE + t] = (unsigned short)(uu.z >> 16);
                    ptile[(i*8+6) * PSTRIDE + t] = (unsigned short)(uu.w & 0xffff);
                    ptile[(i*8+7) * PSTRIDE + t] = (unsigned short)(uu.w >> 16);
                }
            }
            __syncthreads();

            const int pix = pix0 + p;
            const size_t base = (size_t)pix * 256 + h * 32;
            float a[32], kn[32], vv[32];

            // Q
            {
                float S, SS;
                stat_read(P.stats + (size_t)(b * 8 + h) * (NSLOT * 2), S, SS);
                float m = S * INV_CNT;
                float r = rsqrtf(SS * INV_CNT - m * m + 1e-5f);
                float qv[32], ssum = 0.f;
                bf16x32_load(P.qtok + base, qv);
#pragma unroll
                for (int j = 0; j < 32; j++) {
                    float g = r * sqg[h * 32 + j];
                    qv[j] = (qv[j] - m) * g + sqb[h * 32 + j];
                    ssum = fmaf(qv[j], qv[j], ssum);
                }
                float inv = K2 / fmaxf(sqrtf(ssum), 1e-12f);
#pragma unroll
                for (int j = 0; j < 32; j++) a[j] = qv[j] * inv;
            }
            // K
            {
                float S, SS;
                stat_read(P.stats + (size_t)(32 + b * 8 + h) * (NSLOT * 2), S, SS);
                float m = S * INV_CNT;
                float r = rsqrtf(SS * INV_CNT - m * m + 1e-5f);
                float ssum = 0.f;
                bf16x32_load(P.ktok + base, kn);
#pragma unroll
                for (int j = 0; j < 32; j++) {
                    float g = r * skg[h * 32 + j];
                    kn[j] = (kn[j] - m) * g + skb[h * 32 + j];
                    ssum = fmaf(kn[j], kn[j], ssum);
                }
                float inv = 1.f / fmaxf(sqrtf(ssum), 1e-12f);
#pragma unroll
                for (int j = 0; j < 32; j++) kn[j] *= inv;
            }
            bf16x32_load(P.vtok + base, vv);

            const unsigned short* pl = ptile + p * PSTRIDE + h * 32;
            uint4* op = (uint4*)(aT + base);
#pragma unroll
            for (int di = 0; di < 4; di++) {
                // pos slice for these 8 outputs (LDS, 16 B)
                uint4 up = *(const uint4*)(pl + di * 8);
                float pv8[8];
                pv8[0] = bf2f((unsigned short)(up.x & 0xffff)); pv8[1] = bf2f((unsigned short)(up.x >> 16));
                pv8[2] = bf2f((unsigned short)(up.y & 0xffff)); pv8[3] = bf2f((unsigned short)(up.y >> 16));
                pv8[4] = bf2f((unsigned short)(up.z & 0xffff)); pv8[5] = bf2f((unsigned short)(up.z >> 16));
                pv8[6] = bf2f((unsigned short)(up.w & 0xffff)); pv8[7] = bf2f((unsigned short)(up.w >> 16));
                unsigned int od[4];
#pragma unroll
                for (int dp = 0; dp < 4; dp++) {
                    float o2[2];
#pragma unroll
                    for (int dd = 0; dd < 2; dd++) {
                        float ad = a[di * 8 + dp * 2 + dd];
                        float num = 0.f, den = 0.f;
#pragma unroll
                        for (int e = 0; e < 32; e++) {
                            float w = __builtin_amdgcn_exp2f(ad * kn[e]);
                            num = fmaf(w, vv[e], num);
                            den += w;
                        }
                        o2[dd] = num / den + pv8[dp * 2 + dd];
                    }
                    od[dp] = (unsigned)f2bf(o2[0]) | ((unsigned)f2bf(o2[1]) << 16);
                }
                op[di] = make_uint4(od[0], od[1], od[2], od[3]);
            }
        }
    }

    grid.sync();

    // ---------------- Phase 4: output projection (256 tiles), bf16 out + stats
    {
        unsigned short* sA = (unsigned short*)smem;
        unsigned short* sB = (unsigned short*)(smem + 16384);
        const unsigned short* aT = P.xT;
        unsigned short* outb = P.ktok;   // ktok dead after phase 3
        for (int u = bid; u < 256; u += NBg) {
            int bx = u & 31, z2 = u >> 5;
            int ny = z2 & 1, batch = z2 >> 1;
            const unsigned short* A  = aT + (size_t)batch * PLANE;   // token x K
            const unsigned short* Bm = P.wbf + 3 * 65536;            // outch x K
            unsigned short* Y = outb + (size_t)batch * PLANE;
            const int m0 = bx * 128;   // token
            const int n0 = ny * 128;   // outch

            __syncthreads();
            f32x4 acc[4][4];
            mfma_core(A, Bm, m0, n0, acc, sA, sB);

            const int lane = t & 63, wave = t >> 6;
            const int wm = wave >> 1, wn = wave & 1;
            const int cl = lane & 15, qd = lane >> 4;

            float s[2] = {0.f, 0.f}, ss[2] = {0.f, 0.f};
#pragma unroll
            for (int ni = 0; ni < 4; ni++) {
                int oc = n0 + wn * 64 + ni * 16 + cl;
                float bb = P.bp[oc];
#pragma unroll
                for (int mi = 0; mi < 4; mi++) {
                    int tk = m0 + wm * 64 + mi * 16 + qd * 4;
                    float4 o;
                    o.x = acc[mi][ni][0] + bb; o.y = acc[mi][ni][1] + bb;
                    o.z = acc[mi][ni][2] + bb; o.w = acc[mi][ni][3] + bb;
                    s[ni >> 1] += o.x + o.y + o.z + o.w;
                    ss[ni >> 1] += o.x * o.x + o.y * o.y + o.z * o.z + o.w * o.w;
                    uint2 pk;
                    pk.x = (unsigned)f2bf(o.x) | ((unsigned)f2bf(o.y) << 16);
                    pk.y = (unsigned)f2bf(o.z) | ((unsigned)f2bf(o.w) << 16);
                    *(uint2*)&Y[(size_t)oc * HW_ + tk] = pk;
                }
            }
            int g0 = (n0 >> 5) + wn * 2;
            int slot = bx & (NSLOT - 1);
            float* d0 = P.stats + (size_t)(64 + batch * 8 + g0) * (NSLOT * 2) + slot * 2;
            stat_atomic(s[0], ss[0], s[1], ss[1], d0, d0 + NSLOT * 2);
        }
    }

    grid.sync();

    // ---------------- Phase 5: final GroupNorm apply -> fp32 d_out
    {
        const unsigned short* src = P.ktok;
        for (int i4 = bid * 256 + t; i4 < 1048576; i4 += NBg * 256) {
            int idx = i4 * 4;
            int c = (idx >> 12) & 255;
            int bg = ((idx >> 20) << 3) | (c >> 5);
            float S, SS;
            stat_read(P.stats + (size_t)(64 + bg) * (NSLOT * 2), S, SS);
            float mean = S * INV_CNT;
            float rstd = rsqrtf(SS * INV_CNT - mean * mean + 1e-5f);
            float ga = rstd * P.gpg[c], be = P.gpb[c] - mean * ga;
            uint2 u = *(const uint2*)&src[idx];
            float4 v4;
            v4.x = bf2f((unsigned short)(u.x & 0xffff)) * ga + be;
            v4.y = bf2f((unsigned short)(u.x >> 16))    * ga + be;
            v4.z = bf2f((unsigned short)(u.y & 0xffff)) * ga + be;
            v4.w = bf2f((unsigned short)(u.y >> 16))    * ga + be;
            *(float4*)&P.out[idx] = v4;
        }
    }
}

// ---------------------------------------------------------------------------
extern "C" void kernel_launch(void* const* d_in, const int* in_sizes, int n_in,
                              void* d_out, int out_size, void* d_ws, size_t ws_size,
                              hipStream_t stream)
{
    char* ws = (char*)d_ws;
    const size_t MB8 = (size_t)8 * 1024 * 1024;

    MegaParams P;
    P.x   = (const float*)d_in[0];
    P.wq  = (const float*)d_in[1];
    P.gqg = (const float*)d_in[2];
    P.gqb = (const float*)d_in[3];
    P.wk  = (const float*)d_in[4];
    P.gkg = (const float*)d_in[5];
    P.gkb = (const float*)d_in[6];
    P.wv  = (const float*)d_in[7];
    P.wp  = (const float*)d_in[8];
    P.bp  = (const float*)d_in[9];
    P.gpg = (const float*)d_in[10];
    P.gpb = (const float*)d_in[11];
    P.dw1 = (const float*)d_in[12];
    P.db1 = (const float*)d_in[13];
    P.dw2 = (const float*)d_in[14];
    P.db2 = (const float*)d_in[15];
    P.qtok = (unsigned short*)(ws);
    P.ktok = (unsigned short*)(ws + MB8);
    P.vtok = (unsigned short*)(ws + 2 * MB8);
    P.xT   = (unsigned short*)(ws + 3 * MB8);
    P.pos  = (unsigned short*)(ws + 4 * MB8);
    P.wbf  = (unsigned short*)(ws + 5 * MB8);
    P.stats= (float*)(ws + 5 * MB8 + 524288);
    P.out  = (float*)d_out;

    int occ = 0;
    if (hipOccupancyMaxActiveBlocksPerMultiprocessor(&occ, mega_kernel, 256, 0)
        != hipSuccess || occ <= 0) occ = 3;
    int nb = occ * 256;          // 256 CUs on MI355X
    if (nb > 768) nb = 768;

    void* args[] = { (void*)&P };
    hipLaunchCooperativeKernel((const void*)mega_kernel, dim3(nb), dim3(256),
                               args, 0, stream);
}

// Round 11
// 172.088 us; speedup vs baseline: 2.6353x; 2.6353x over previous
//
#include <hip/hip_runtime.h>
#include <math.h>
#include <stdint.h>

#define C_ 256
#define HW_ 4096
#define PLANE (C_*HW_)   // 1048576 elements per batch
#define INV_CNT (1.f / 131072.f)
#define NSLOT 16         // atomic spread slots per (tensor,b,g)
#define PSTRIDE 264      // padded LDS stride (shorts) for pos transpose tile

typedef __attribute__((ext_vector_type(8))) short bf16x8;
typedef __attribute__((ext_vector_type(4))) float f32x4;

__device__ __forceinline__ unsigned short f2bf(float f) {
    union { float f; unsigned int u; } v; v.f = f;
    unsigned int r = v.u + 0x7fffu + ((v.u >> 16) & 1u);
    return (unsigned short)(r >> 16);
}

__device__ __forceinline__ float bf2f(unsigned short u) {
    return __uint_as_float(((unsigned)u) << 16);
}

__device__ __forceinline__ void load_lds16(const void* g, void* l) {
    __builtin_amdgcn_global_load_lds(
        (const __attribute__((address_space(1))) unsigned int*)g,
        (__attribute__((address_space(3))) unsigned int*)l, 16, 0, 0);
}

__device__ __forceinline__ float gelu_exact(float v) {
    return 0.5f * v * (1.f + erff(v * 0.70710678118654752f));
}

// ---------------------------------------------------------------------------
// Prep kernel, grid 2048:
//  blocks [0,1024):   transpose x -> xT bf16 [n][c] + weight cvt + stats zero
//  blocks [1024,2048): depthwise 3x3 -> GELU -> depthwise 3x3 -> pos bf16
// Both branches read only x; single launch for L2 sharing and -1 launch.
// ---------------------------------------------------------------------------
__global__ __launch_bounds__(256) void prep_kernel(
    const float* __restrict__ x, unsigned short* __restrict__ xT,
    const float* __restrict__ wq, const float* __restrict__ wk,
    const float* __restrict__ wv, const float* __restrict__ wp,
    unsigned short* __restrict__ wbf, float* __restrict__ stats,
    const float* __restrict__ dw1, const float* __restrict__ db1,
    const float* __restrict__ dw2, const float* __restrict__ db2,
    unsigned short* __restrict__ pos)
{
    __shared__ __align__(16) char smem[66 * 68 * 4 * 2];   // 35904 B arena
    const int bid = blockIdx.x;
    const int t = threadIdx.x;

    if (bid < 1024) {
        // ---- transpose + weight cvt ----
        float (*tile)[65] = (float(*)[65])smem;
        {
            int widx = bid * 256 + t;
            const float* s = (widx < 65536) ? wq : (widx < 131072) ? wk
                           : (widx < 196608) ? wv : wp;
            wbf[widx] = f2bf(s[widx & 65535]);
            if (bid == 0) {
#pragma unroll
                for (int i = 0; i < 12; i++) stats[t + i * 256] = 0.f;
            }
        }
        int b = bid >> 8, c0 = ((bid >> 6) & 3) * 64, n0 = (bid & 63) * 64;
        const float* s = x + (size_t)b * PLANE;
        unsigned short* d = xT + (size_t)b * PLANE;
        int r = t >> 6, col = t & 63;
#pragma unroll
        for (int i = 0; i < 16; i++)
            tile[r + i * 4][col] = s[(size_t)(c0 + r + i * 4) * HW_ + n0 + col];
        __syncthreads();
#pragma unroll
        for (int i = 0; i < 16; i++)
            d[(size_t)(n0 + r + i * 4) * 256 + c0 + col] = f2bf(tile[col][r + i * 4]);
    } else {
        // ---- depthwise conv chain ----
        float* xs = (float*)smem;
        float* ps = xs + 66 * 68;
        const int bc = bid - 1024;      // b*256 + c
        const int c = bc & 255;
        const float* plane = x + (size_t)bc * 4096;

        float w1[9], w2[9];
#pragma unroll
        for (int i = 0; i < 9; i++) { w1[i] = dw1[c * 9 + i]; w2[i] = dw2[c * 9 + i]; }
        const float b1 = db1[c], b2 = db2[c];

        for (int i = t; i < 66 * 66; i += 256) {
            int r = i / 66, cc = i - r * 66;
            int gr = r - 1, gc = cc - 1;
            float v = 0.f;
            if ((unsigned)gr < 64u && (unsigned)gc < 64u) v = plane[gr * 64 + gc];
            xs[r * 68 + cc] = v;
        }
        __syncthreads();

        for (int i = t; i < 66 * 66; i += 256) {
            int pr = i / 66, pc = i - pr * 66;
            int gr = pr - 1, gc = pc - 1;
            float val = 0.f;
            if ((unsigned)gr < 64u && (unsigned)gc < 64u) {
                float s = b1;
#pragma unroll
                for (int ky = 0; ky < 3; ky++)
#pragma unroll
                    for (int kx = 0; kx < 3; kx++)
                        s += w1[ky * 3 + kx] * xs[(gr + ky) * 68 + (gc + kx)];
                val = gelu_exact(s);
            }
            ps[pr * 68 + pc] = val;
        }
        __syncthreads();

        for (int i = t; i < 4096; i += 256) {
            int orow = i >> 6, ocol = i & 63;
            float s = b2;
#pragma unroll
            for (int ky = 0; ky < 3; ky++)
#pragma unroll
                for (int kx = 0; kx < 3; kx++)
                    s += w2[ky * 3 + kx] * ps[(orow + ky) * 68 + (ocol + kx)];
            pos[(size_t)bc * 4096 + i] = f2bf(s);
        }
    }
}

// ---------------------------------------------------------------------------
// MFMA core, BK=64 as two BK=32 sub-buffers. LDS 32 KB.
// ---------------------------------------------------------------------------
__device__ __forceinline__ void mfma_core(
    const unsigned short* __restrict__ A,
    const unsigned short* __restrict__ Bm,
    int m0, int n0, f32x4 (&acc)[4][4],
    unsigned short* sA, unsigned short* sB)   // each 2*128*32
{
    const int t = threadIdx.x;
    const int lane = t & 63, wave = t >> 6;

#pragma unroll
    for (int i = 0; i < 4; i++)
#pragma unroll
        for (int j = 0; j < 4; j++) acc[i][j] = (f32x4)0.f;

    const int srow = wave * 32 + (lane >> 2);
    const int scol = (lane & 3) * 8;
    const unsigned short* ga = A  + (size_t)(m0 + srow) * 256 + scol;
    const unsigned short* gb = Bm + (size_t)(n0 + srow) * 256 + scol;
    const int lbase = (wave * 32) * 32;

    const int wm = wave >> 1, wn = wave & 1;
    const int fr = lane & 15, kg = lane >> 4;

    for (int k0 = 0; k0 < 256; k0 += 64) {
        if (k0) __syncthreads();
        load_lds16(ga + k0,            sA + lbase);
        load_lds16(ga + k0 + 16 * 256, sA + lbase + 16 * 32);
        load_lds16(gb + k0,            sB + lbase);
        load_lds16(gb + k0 + 16 * 256, sB + lbase + 16 * 32);
        load_lds16(ga + k0 + 32,            sA + 4096 + lbase);
        load_lds16(ga + k0 + 32 + 16 * 256, sA + 4096 + lbase + 16 * 32);
        load_lds16(gb + k0 + 32,            sB + 4096 + lbase);
        load_lds16(gb + k0 + 32 + 16 * 256, sB + 4096 + lbase + 16 * 32);
        __syncthreads();

#pragma unroll
        for (int kk = 0; kk < 2; kk++) {
            bf16x8 af[4], bfr[4];
#pragma unroll
            for (int i = 0; i < 4; i++) {
                af[i]  = *(const bf16x8*)(sA + kk * 4096 + (wm * 64 + i * 16 + fr) * 32 + kg * 8);
                bfr[i] = *(const bf16x8*)(sB + kk * 4096 + (wn * 64 + i * 16 + fr) * 32 + kg * 8);
            }
#pragma unroll
            for (int mi = 0; mi < 4; mi++)
#pragma unroll
                for (int ni = 0; ni < 4; ni++)
                    acc[mi][ni] = __builtin_amdgcn_mfma_f32_16x16x32_bf16(
                        af[mi], bfr[ni], acc[mi][ni], 0, 0, 0);
        }
    }
}

__device__ __forceinline__ void stat_atomic(
    float s0, float ss0, float s1, float ss1, float* d0, float* d1)
{
#pragma unroll
    for (int off = 32; off >= 1; off >>= 1) {
        s0  += __shfl_down(s0, off);  ss0 += __shfl_down(ss0, off);
        s1  += __shfl_down(s1, off);  ss1 += __shfl_down(ss1, off);
    }
    if ((threadIdx.x & 63) == 0) {
        atomicAdd(d0, s0); atomicAdd(d0 + 1, ss0);
        atomicAdd(d1, s1); atomicAdd(d1 + 1, ss1);
    }
}

__device__ __forceinline__ void stat_read(const float* sp, float& S, float& SS) {
    S = 0.f; SS = 0.f;
#pragma unroll
    for (int i = 0; i < NSLOT; i++) { S += sp[i * 2]; SS += sp[i * 2 + 1]; }
}

// ---------------------------------------------------------------------------
// q/k/v: A = W (outch rows). Y token-major bf16 [token][outch].
// grid (2, 32, 12): x=outch-tile, y=token.
// ---------------------------------------------------------------------------
__global__ __launch_bounds__(256) void gemm_qkv_mfma(
    const unsigned short* __restrict__ wbf, const unsigned short* __restrict__ xT,
    unsigned short* __restrict__ q, unsigned short* __restrict__ k,
    unsigned short* __restrict__ v, float* __restrict__ stats)
{
    __shared__ __align__(16) unsigned short sA[2 * 128 * 32];
    __shared__ __align__(16) unsigned short sB[2 * 128 * 32];
    int z = blockIdx.z;
    int batch = z & 3, which = z >> 2;
    unsigned short* Y = ((which == 0) ? q : (which == 1) ? k : v)
                        + (size_t)batch * PLANE;
    const unsigned short* A  = wbf + which * 65536;          // outch x K
    const unsigned short* Bm = xT + (size_t)batch * PLANE;   // token x K
    const int m0 = blockIdx.x * 128;   // outch
    const int n0 = blockIdx.y * 128;   // token

    f32x4 acc[4][4];
    mfma_core(A, Bm, m0, n0, acc, sA, sB);

    const int lane = threadIdx.x & 63, wave = threadIdx.x >> 6;
    const int wm = wave >> 1, wn = wave & 1;
    const int cl = lane & 15, qd = lane >> 4;

    if (which < 2) {
        float s[2] = {0.f, 0.f}, ss[2] = {0.f, 0.f};
#pragma unroll
        for (int mi = 0; mi < 4; mi++)
#pragma unroll
            for (int ni = 0; ni < 4; ni++)
#pragma unroll
                for (int r = 0; r < 4; r++) {
                    float vv = acc[mi][ni][r];
                    s[mi >> 1] += vv; ss[mi >> 1] += vv * vv;
                }
        int g0 = (m0 >> 5) + wm * 2;
        int slot = blockIdx.y & (NSLOT - 1);
        float* d0 = stats + (size_t)(which * 32 + batch * 8 + g0) * (NSLOT * 2) + slot * 2;
        stat_atomic(s[0], ss[0], s[1], ss[1], d0, d0 + NSLOT * 2);
    }

#pragma unroll
    for (int mi = 0; mi < 4; mi++) {
        int oc = m0 + wm * 64 + mi * 16 + qd * 4;
#pragma unroll
        for (int ni = 0; ni < 4; ni++) {
            int token = n0 + wn * 64 + ni * 16 + cl;
            uint2 pk;
            pk.x = (unsigned)f2bf(acc[mi][ni][0]) | ((unsigned)f2bf(acc[mi][ni][1]) << 16);
            pk.y = (unsigned)f2bf(acc[mi][ni][2]) | ((unsigned)f2bf(acc[mi][ni][3]) << 16);
            *(uint2*)&Y[(size_t)token * 256 + oc] = pk;
        }
    }
}

// ---------------------------------------------------------------------------
// final projection: A = aT (token rows). Output bf16 [outch][token] + stats
// from pre-rounding fp32. grid (32, 2, 4)
// ---------------------------------------------------------------------------
__global__ __launch_bounds__(256) void gemm_out_mfma(
    const unsigned short* __restrict__ wbf, const unsigned short* __restrict__ aT,
    const float* __restrict__ bp, unsigned short* __restrict__ yb,
    float* __restrict__ stats)
{
    __shared__ __align__(16) unsigned short sA[2 * 128 * 32];
    __shared__ __align__(16) unsigned short sB[2 * 128 * 32];
    int batch = blockIdx.z;
    const unsigned short* A  = aT + (size_t)batch * PLANE;   // token x K
    const unsigned short* Bm = wbf + 3 * 65536;              // outch x K
    unsigned short* Y = yb + (size_t)batch * PLANE;
    const int m0 = blockIdx.x * 128;   // token
    const int n0 = blockIdx.y * 128;   // outch

    f32x4 acc[4][4];
    mfma_core(A, Bm, m0, n0, acc, sA, sB);

    const int lane = threadIdx.x & 63, wave = threadIdx.x >> 6;
    const int wm = wave >> 1, wn = wave & 1;
    const int cl = lane & 15, qd = lane >> 4;

    float s[2] = {0.f, 0.f}, ss[2] = {0.f, 0.f};
#pragma unroll
    for (int ni = 0; ni < 4; ni++) {
        int oc = n0 + wn * 64 + ni * 16 + cl;
        float bb = bp[oc];
#pragma unroll
        for (int mi = 0; mi < 4; mi++) {
            int tk = m0 + wm * 64 + mi * 16 + qd * 4;
            float4 o;
            o.x = acc[mi][ni][0] + bb; o.y = acc[mi][ni][1] + bb;
            o.z = acc[mi][ni][2] + bb; o.w = acc[mi][ni][3] + bb;
            s[ni >> 1] += o.x + o.y + o.z + o.w;
            ss[ni >> 1] += o.x * o.x + o.y * o.y + o.z * o.z + o.w * o.w;
            uint2 pk;
            pk.x = (unsigned)f2bf(o.x) | ((unsigned)f2bf(o.y) << 16);
            pk.y = (unsigned)f2bf(o.z) | ((unsigned)f2bf(o.w) << 16);
            *(uint2*)&Y[(size_t)oc * HW_ + tk] = pk;
        }
    }
    int g0 = (n0 >> 5) + wn * 2;
    int slot = blockIdx.x & (NSLOT - 1);
    float* d0 = stats + (size_t)(64 + batch * 8 + g0) * (NSLOT * 2) + slot * 2;
    stat_atomic(s[0], ss[0], s[1], ss[1], d0, d0 + NSLOT * 2);
}

// ---------------------------------------------------------------------------
// Attention + pos-add, token-major bf16 in/out. Thread = one (pixel, head).
// ---------------------------------------------------------------------------
__device__ __forceinline__ void bf16x32_load(const unsigned short* p, float* o) {
    const uint4* u4 = (const uint4*)p;
#pragma unroll
    for (int i = 0; i < 4; i++) {
        uint4 u = u4[i];
        o[i*8+0] = __uint_as_float(u.x << 16); o[i*8+1] = __uint_as_float(u.x & 0xffff0000u);
        o[i*8+2] = __uint_as_float(u.y << 16); o[i*8+3] = __uint_as_float(u.y & 0xffff0000u);
        o[i*8+4] = __uint_as_float(u.z << 16); o[i*8+5] = __uint_as_float(u.z & 0xffff0000u);
        o[i*8+6] = __uint_as_float(u.w << 16); o[i*8+7] = __uint_as_float(u.w & 0xffff0000u);
    }
}

__global__ __launch_bounds__(256) void attn_tok_kernel(
    const unsigned short* __restrict__ qtok, const unsigned short* __restrict__ ktok,
    const unsigned short* __restrict__ vtok, const unsigned short* __restrict__ pos,
    const float* __restrict__ stats,
    const float* __restrict__ gqg, const float* __restrict__ gqb,
    const float* __restrict__ gkg, const float* __restrict__ gkb,
    unsigned short* __restrict__ out)
{
    __shared__ float sqg[256], sqb[256], skg[256], skb[256];
    __shared__ unsigned short ptile[32 * PSTRIDE];   // pos^T tile: [pixel][chan]
    const int t = threadIdx.x;
    sqg[t] = gqg[t]; sqb[t] = gqb[t]; skg[t] = gkg[t]; skb[t] = gkb[t];

    const int pix0 = blockIdx.x * 32;
    const int b = pix0 >> 12;
    const int n0 = pix0 & 4095;

    {
        const uint4* prow = (const uint4*)(pos + (size_t)b * PLANE + (size_t)t * HW_ + n0);
#pragma unroll
        for (int i = 0; i < 4; i++) {
            uint4 u = prow[i];
            ptile[(i*8+0) * PSTRIDE + t] = (unsigned short)(u.x & 0xffff);
            ptile[(i*8+1) * PSTRIDE + t] = (unsigned short)(u.x >> 16);
            ptile[(i*8+2) * PSTRIDE + t] = (unsigned short)(u.y & 0xffff);
            ptile[(i*8+3) * PSTRIDE + t] = (unsigned short)(u.y >> 16);
            ptile[(i*8+4) * PSTRIDE + t] = (unsigned short)(u.z & 0xffff);
            ptile[(i*8+5) * PSTRIDE + t] = (unsigned short)(u.z >> 16);
            ptile[(i*8+6) * PSTRIDE + t] = (unsigned short)(u.w & 0xffff);
            ptile[(i*8+7) * PSTRIDE + t] = (unsigned short)(u.w >> 16);
        }
    }
    __syncthreads();

    const int h = t & 7;
    const int p = t >> 3;
    const int pix = pix0 + p;
    const size_t base = (size_t)pix * 256 + h * 32;
    const float K2 = 0.17677669529663687f * 1.4426950408889634f; // scale*log2e

    float a[32], kn[32], vv[32], pv[32];
    bf16x32_load((const unsigned short*)&ptile[p * PSTRIDE + h * 32], pv);

    // Q
    {
        float S, SS;
        stat_read(stats + (size_t)(b * 8 + h) * (NSLOT * 2), S, SS);
        float m = S * INV_CNT;
        float r = rsqrtf(SS * INV_CNT - m * m + 1e-5f);
        float qv[32], ssum = 0.f;
        bf16x32_load(qtok + base, qv);
#pragma unroll
        for (int j = 0; j < 32; j++) {
            float g = r * sqg[h * 32 + j];
            qv[j] = (qv[j] - m) * g + sqb[h * 32 + j];
            ssum = fmaf(qv[j], qv[j], ssum);
        }
        float inv = K2 / fmaxf(sqrtf(ssum), 1e-12f);
#pragma unroll
        for (int j = 0; j < 32; j++) a[j] = qv[j] * inv;
    }
    // K
    {
        float S, SS;
        stat_read(stats + (size_t)(32 + b * 8 + h) * (NSLOT * 2), S, SS);
        float m = S * INV_CNT;
        float r = rsqrtf(SS * INV_CNT - m * m + 1e-5f);
        float ssum = 0.f;
        bf16x32_load(ktok + base, kn);
#pragma unroll
        for (int j = 0; j < 32; j++) {
            float g = r * skg[h * 32 + j];
            kn[j] = (kn[j] - m) * g + skb[h * 32 + j];
            ssum = fmaf(kn[j], kn[j], ssum);
        }
        float inv = 1.f / fmaxf(sqrtf(ssum), 1e-12f);
#pragma unroll
        for (int j = 0; j < 32; j++) kn[j] *= inv;
    }
    bf16x32_load(vtok + base, vv);

    uint4* op = (uint4*)(out + base);
#pragma unroll
    for (int di = 0; di < 4; di++) {
        unsigned int od[4];
#pragma unroll
        for (int dp = 0; dp < 4; dp++) {
            float o2[2];
#pragma unroll
            for (int dd = 0; dd < 2; dd++) {
                int d = di * 8 + dp * 2 + dd;
                float ad = a[d];
                float num = 0.f, den = 0.f;
#pragma unroll
                for (int e = 0; e < 32; e++) {
                    float w = __builtin_amdgcn_exp2f(ad * kn[e]);
                    num = fmaf(w, vv[e], num);
                    den += w;
                }
                o2[dd] = num / den + pv[d];
            }
            od[dp] = (unsigned)f2bf(o2[0]) | ((unsigned)f2bf(o2[1]) << 16);
        }
        op[di] = make_uint4(od[0], od[1], od[2], od[3]);
    }
}

// ---------------------------------------------------------------------------
// Final GroupNorm apply: read bf16 pre-GN, write fp32 d_out
// ---------------------------------------------------------------------------
__global__ __launch_bounds__(256) void gn_apply_kernel(
    const unsigned short* __restrict__ src, float* __restrict__ y,
    const float* __restrict__ stats,
    const float* __restrict__ gamma, const float* __restrict__ beta)
{
    int i4 = blockIdx.x * 256 + threadIdx.x;
    int idx = i4 * 4;
    int c = (idx >> 12) & 255;
    int bg = ((idx >> 20) << 3) | (c >> 5);
    float S, SS;
    stat_read(stats + (size_t)(64 + bg) * (NSLOT * 2), S, SS);
    float mean = S * INV_CNT;
    float rstd = rsqrtf(SS * INV_CNT - mean * mean + 1e-5f);
    float ga = rstd * gamma[c], be = beta[c] - mean * ga;
    uint2 u = *(const uint2*)&src[idx];
    float4 v4;
    v4.x = bf2f((unsigned short)(u.x & 0xffff)) * ga + be;
    v4.y = bf2f((unsigned short)(u.x >> 16))    * ga + be;
    v4.z = bf2f((unsigned short)(u.y & 0xffff)) * ga + be;
    v4.w = bf2f((unsigned short)(u.y >> 16))    * ga + be;
    *(float4*)&y[idx] = v4;
}

// ---------------------------------------------------------------------------
extern "C" void kernel_launch(void* const* d_in, const int* in_sizes, int n_in,
                              void* d_out, int out_size, void* d_ws, size_t ws_size,
                              hipStream_t stream)
{
    const float* x   = (const float*)d_in[0];
    const float* wq  = (const float*)d_in[1];
    const float* gqg = (const float*)d_in[2];
    const float* gqb = (const float*)d_in[3];
    const float* wk  = (const float*)d_in[4];
    const float* gkg = (const float*)d_in[5];
    const float* gkb = (const float*)d_in[6];
    const float* wv  = (const float*)d_in[7];
    const float* wp  = (const float*)d_in[8];
    const float* bp  = (const float*)d_in[9];
    const float* gpg = (const float*)d_in[10];
    const float* gpb = (const float*)d_in[11];
    const float* dw1 = (const float*)d_in[12];
    const float* db1 = (const float*)d_in[13];
    const float* dw2 = (const float*)d_in[14];
    const float* db2 = (const float*)d_in[15];
    float* out = (float*)d_out;

    char* ws = (char*)d_ws;
    const size_t MB8 = (size_t)8 * 1024 * 1024;
    unsigned short* qtok = (unsigned short*)(ws);              // 8 MB bf16 [n][c]
    unsigned short* ktok = (unsigned short*)(ws + MB8);        // 8 MB
    unsigned short* vtok = (unsigned short*)(ws + 2 * MB8);    // 8 MB
    unsigned short* xT   = (unsigned short*)(ws + 3 * MB8);    // 8 MB
    unsigned short* aT   = xT;                                 // attn writes over xT (dead)
    unsigned short* outb = ktok;                               // reuse after attn
    unsigned short* pos  = (unsigned short*)(ws + 4 * MB8);    // 8 MB bf16 channel-major
    unsigned short* wbf  = (unsigned short*)(ws + 5 * MB8);    // 512 KB
    float*          stats= (float*)(ws + 5 * MB8 + 524288);    // 3072 floats

    dim3 blk(256);
    prep_kernel<<<dim3(2048), blk, 0, stream>>>(x, xT, wq, wk, wv, wp, wbf, stats,
                                                dw1, db1, dw2, db2, pos);
    gemm_qkv_mfma<<<dim3(2, 32, 12), blk, 0, stream>>>(wbf, xT, qtok, ktok, vtok, stats);
    attn_tok_kernel<<<dim3(512), blk, 0, stream>>>(qtok, ktok, vtok, pos, stats,
                                                   gqg, gqb, gkg, gkb, aT);
    gemm_out_mfma<<<dim3(32, 2, 4), blk, 0, stream>>>(wbf, aT, bp, outb, stats);
    gn_apply_kernel<<<dim3(4096), blk, 0, stream>>>(outb, out, stats, gpg, gpb);
}